// Round 5
// baseline (282.516 us; speedup 1.0000x reference)
//
#include <hip/hip_runtime.h>
#include <stdint.h>

// PerfeCT membership: out[i] = +5.0 if (h,r,t) query triple appears in data, else -5.0.
// CRITICAL: the harness evaluates the reference with int32 inputs, so
// _triple_key overflows int32: key32 = ((h*15000 + r)*15000 + t) mod 2^32.
// We MUST replicate that wraparound (uint32 arithmetic == int32 bit pattern) —
// exact 42-bit keys diverge from the reference on ~233 collision queries (round-4 fail).
// Strategy: hash-set of the 100K QUERY key32s (3 MB, L2-resident), one streaming
// pass over the 120 MB data marking hits. Roofline = one read of data ~= 19 us.

static __device__ __forceinline__ uint32_t mix32(uint32_t x) {
    // murmur3 finalizer — full-avalanche 32-bit mix for table index
    x ^= x >> 16; x *= 0x85ebca6bu;
    x ^= x >> 13; x *= 0xc2b2ae35u;
    x ^= x >> 16;
    return x;
}

static __device__ __forceinline__ uint32_t key32(int h, int r, int t) {
    // Matches int32 reference arithmetic: wrap on the second multiply.
    return ((uint32_t)h * 15000u + (uint32_t)r) * 15000u + (uint32_t)t;
}

__global__ void k_zero(uint32_t* __restrict__ p, int nwords) {
    int stride = gridDim.x * blockDim.x;
    for (int i = blockIdx.x * blockDim.x + threadIdx.x; i < nwords; i += stride)
        p[i] = 0u;
}

// Pass 1: insert query keys (stored as key32+1 in a u64 slot; 0 = empty — no
// sentinel collision since key32+1 <= 2^32). Duplicates dedupe via CAS.
__global__ void k_insert(const int* __restrict__ qh,
                         const int* __restrict__ qr,
                         const int* __restrict__ qt,
                         unsigned long long* __restrict__ keys,
                         uint32_t mask, int Q) {
    int i = blockIdx.x * blockDim.x + threadIdx.x;
    if (i >= Q) return;
    uint32_t key = key32(qh[i], qr[i], qt[i]);
    unsigned long long k1 = (unsigned long long)key + 1ull;
    uint32_t slot = mix32(key) & mask;
    while (true) {
        unsigned long long prev = atomicCAS(&keys[slot], 0ull, k1);
        if (prev == 0ull || prev == k1) return;
        slot = (slot + 1) & mask;
    }
}

static __device__ __forceinline__ void probe_mark(uint32_t key,
                                                  const unsigned long long* __restrict__ keys,
                                                  uint32_t* __restrict__ flags,
                                                  uint32_t mask) {
    unsigned long long k1 = (unsigned long long)key + 1ull;
    uint32_t slot = mix32(key) & mask;
    while (true) {
        unsigned long long v = keys[slot];
        if (v == 0ull) return;                      // empty -> not a queried key
        if (v == k1) { flags[slot] = 1u; return; }  // idempotent flag store
        slot = (slot + 1) & mask;
    }
}

// Pass 2: stream data triples, 4 per thread via int4, probe table, mark hits.
__global__ void k_scan(const int* __restrict__ dh,
                       const int* __restrict__ dr,
                       const int* __restrict__ dt,
                       const unsigned long long* __restrict__ keys,
                       uint32_t* __restrict__ flags,
                       uint32_t mask, int nquad, int N) {
    int stride = gridDim.x * blockDim.x;
    for (int j = blockIdx.x * blockDim.x + threadIdx.x; j < nquad; j += stride) {
        int4 h4 = ((const int4*)dh)[j];
        int4 r4 = ((const int4*)dr)[j];
        int4 t4 = ((const int4*)dt)[j];
        probe_mark(key32(h4.x, r4.x, t4.x), keys, flags, mask);
        probe_mark(key32(h4.y, r4.y, t4.y), keys, flags, mask);
        probe_mark(key32(h4.z, r4.z, t4.z), keys, flags, mask);
        probe_mark(key32(h4.w, r4.w, t4.w), keys, flags, mask);
    }
    // tail (N not divisible by 4)
    int tail = N & 3;
    if (tail && blockIdx.x == 0 && threadIdx.x < (unsigned)tail) {
        int j = N - 1 - (int)threadIdx.x;
        probe_mark(key32(dh[j], dr[j], dt[j]), keys, flags, mask);
    }
}

// Pass 3: each query re-probes its own key (present by construction), reads the flag.
__global__ void k_out(const int* __restrict__ qh,
                      const int* __restrict__ qr,
                      const int* __restrict__ qt,
                      const unsigned long long* __restrict__ keys,
                      const uint32_t* __restrict__ flags,
                      float* __restrict__ out,
                      uint32_t mask, int Q) {
    int i = blockIdx.x * blockDim.x + threadIdx.x;
    if (i >= Q) return;
    uint32_t key = key32(qh[i], qr[i], qt[i]);
    unsigned long long k1 = (unsigned long long)key + 1ull;
    uint32_t slot = mix32(key) & mask;
    float v = -5.0f;
    while (true) {
        unsigned long long kv = keys[slot];
        if (kv == k1) { v = flags[slot] ? 5.0f : -5.0f; break; }
        if (kv == 0ull) break;  // shouldn't happen (key was inserted)
        slot = (slot + 1) & mask;
    }
    out[i] = v;
}

extern "C" void kernel_launch(void* const* d_in, const int* in_sizes, int n_in,
                              void* d_out, int out_size, void* d_ws, size_t ws_size,
                              hipStream_t stream) {
    const int* qh = (const int*)d_in[0];
    const int* qr = (const int*)d_in[1];
    const int* qt = (const int*)d_in[2];
    const int* data = (const int*)d_in[3];
    int Q = in_sizes[0];
    int N = in_sizes[3] / 3;
    const int* dh = data;
    const int* dr = data + (size_t)N;
    const int* dt = data + 2 * (size_t)N;
    float* out = (float*)d_out;

    // Table: 2^18 slots (load factor ~0.38); 8B keys + 4B flags = 3 MB.
    // NEVER drop below 2^17 (131072 slots): 100K keys must fit or k_insert livelocks.
    int tbits = 18;
    while (tbits > 17 && ((size_t)12 << tbits) > ws_size) tbits--;
    uint32_t tsize = 1u << tbits;
    uint32_t mask = tsize - 1u;
    unsigned long long* keys = (unsigned long long*)d_ws;
    uint32_t* flags = (uint32_t*)((char*)d_ws + (size_t)tsize * 8);

    int zwords = (int)(tsize * 3);  // tsize*12 bytes / 4
    k_zero<<<(zwords + 255) / 256, 256, 0, stream>>>((uint32_t*)d_ws, zwords);

    int qblocks = (Q + 255) / 256;
    k_insert<<<qblocks, 256, 0, stream>>>(qh, qr, qt, keys, mask, Q);

    int nquad = N / 4;
    int sblocks = (nquad + 255) / 256;
    if (sblocks > 2048) sblocks = 2048;
    k_scan<<<sblocks, 256, 0, stream>>>(dh, dr, dt, keys, flags, mask, nquad, N);

    k_out<<<qblocks, 256, 0, stream>>>(qh, qr, qt, keys, flags, out, mask, Q);
}

// Round 6
// 238.109 us; speedup vs baseline: 1.1865x; 1.1865x over previous
//
#include <hip/hip_runtime.h>
#include <stdint.h>

// PerfeCT membership: out[i] = +5.0 if (h,r,t) appears in data, else -5.0.
// Keys replicate the reference's int32 overflow: key32 = ((h*15000+r)*15000+t) mod 2^32.
// Round-5 diagnosis: k_scan latency-bound (VGPR=12, VALUBusy 10%, nothing saturated) —
// divergent probe loop exposed one full memory latency per probe with MLP=1.
// Fix: 512KB bloom bitmap front end (L2-hot, ~150x reuse/line) tested with independent
// loads; exact u32 table (EMPTY=0xFFFFFFFF) probed only on ~2.4% bloom hits.

typedef int iv4 __attribute__((ext_vector_type(4)));

#define EMPTY 0xFFFFFFFFu

static __device__ __forceinline__ uint32_t mix32(uint32_t x) {
    x ^= x >> 16; x *= 0x85ebca6bu;
    x ^= x >> 13; x *= 0xc2b2ae35u;
    x ^= x >> 16;
    return x;
}
static __device__ __forceinline__ uint32_t hash2(uint32_t x) {   // decorrelated table hash
    return mix32(x ^ 0x9E3779B9u);
}
static __device__ __forceinline__ uint32_t key32(int h, int r, int t) {
    return ((uint32_t)h * 15000u + (uint32_t)r) * 15000u + (uint32_t)t;
}

// Layout in ws: [bloom][flagbits][sent(4B)+pad252][keys]; first zeroWords words = 0,
// then table words = EMPTY.
__global__ void k_zero(uint32_t* __restrict__ p, int zeroWords, int totalWords) {
    int stride = gridDim.x * blockDim.x;
    for (int i = blockIdx.x * blockDim.x + threadIdx.x; i < totalWords; i += stride)
        p[i] = (i < zeroWords) ? 0u : EMPTY;
}

__global__ void k_insert(const int* __restrict__ qh, const int* __restrict__ qr,
                         const int* __restrict__ qt,
                         uint32_t* __restrict__ bloom, uint32_t* __restrict__ keys,
                         uint32_t* __restrict__ sent,
                         uint32_t bmask, uint32_t tmask, int Q) {
    int i = blockIdx.x * blockDim.x + threadIdx.x;
    if (i >= Q) return;
    uint32_t key = key32(qh[i], qr[i], qt[i]);
    if (key == EMPTY) return;                 // sentinel query: k_out reads sent word directly
    uint32_t b = mix32(key) & bmask;
    atomicOr(&bloom[b >> 5], 1u << (b & 31));
    uint32_t slot = hash2(key) & tmask;
    while (true) {
        uint32_t prev = atomicCAS(&keys[slot], EMPTY, key);
        if (prev == EMPTY || prev == key) return;
        slot = (slot + 1) & tmask;
    }
}

static __device__ __forceinline__ void probe_mark(uint32_t key,
                                                  const uint32_t* __restrict__ keys,
                                                  uint32_t* __restrict__ flagbits,
                                                  uint32_t tmask) {
    uint32_t slot = hash2(key) & tmask;
    while (true) {
        uint32_t v = keys[slot];
        if (v == key) { atomicOr(&flagbits[slot >> 5], 1u << (slot & 31)); return; }
        if (v == EMPTY) return;
        slot = (slot + 1) & tmask;
    }
}

// Stream 4 triples/thread; all 3 data loads + 4 bloom-word loads are independent (MLP~7).
__global__ void k_scan(const int* __restrict__ dh, const int* __restrict__ dr,
                       const int* __restrict__ dt,
                       const uint32_t* __restrict__ bloom,
                       const uint32_t* __restrict__ keys,
                       uint32_t* __restrict__ flagbits, uint32_t* __restrict__ sent,
                       uint32_t bmask, uint32_t tmask, int nquad, int N) {
    int stride = gridDim.x * blockDim.x;
    for (int j = blockIdx.x * blockDim.x + threadIdx.x; j < nquad; j += stride) {
        iv4 h4 = ((const iv4*)dh)[j];
        iv4 r4 = ((const iv4*)dr)[j];
        iv4 t4 = ((const iv4*)dt)[j];
        uint32_t k0 = key32(h4.x, r4.x, t4.x);
        uint32_t k1 = key32(h4.y, r4.y, t4.y);
        uint32_t k2 = key32(h4.z, r4.z, t4.z);
        uint32_t k3 = key32(h4.w, r4.w, t4.w);
        uint32_t b0 = mix32(k0) & bmask, b1 = mix32(k1) & bmask;
        uint32_t b2 = mix32(k2) & bmask, b3 = mix32(k3) & bmask;
        // Independent bloom-word loads (issued together, one waitcnt).
        uint32_t w0 = bloom[b0 >> 5];
        uint32_t w1 = bloom[b1 >> 5];
        uint32_t w2 = bloom[b2 >> 5];
        uint32_t w3 = bloom[b3 >> 5];
        if (k0 == EMPTY) *sent = 1u; else if ((w0 >> (b0 & 31)) & 1u) probe_mark(k0, keys, flagbits, tmask);
        if (k1 == EMPTY) *sent = 1u; else if ((w1 >> (b1 & 31)) & 1u) probe_mark(k1, keys, flagbits, tmask);
        if (k2 == EMPTY) *sent = 1u; else if ((w2 >> (b2 & 31)) & 1u) probe_mark(k2, keys, flagbits, tmask);
        if (k3 == EMPTY) *sent = 1u; else if ((w3 >> (b3 & 31)) & 1u) probe_mark(k3, keys, flagbits, tmask);
    }
    int tail = N & 3;
    if (tail && blockIdx.x == 0 && threadIdx.x < (unsigned)tail) {
        int j = N - 1 - (int)threadIdx.x;
        uint32_t k = key32(dh[j], dr[j], dt[j]);
        if (k == EMPTY) *sent = 1u;
        else probe_mark(k, keys, flagbits, tmask);   // skip bloom on tail
    }
}

__global__ void k_out(const int* __restrict__ qh, const int* __restrict__ qr,
                      const int* __restrict__ qt,
                      const uint32_t* __restrict__ keys,
                      const uint32_t* __restrict__ flagbits,
                      const uint32_t* __restrict__ sent,
                      float* __restrict__ out, uint32_t tmask, int Q) {
    int i = blockIdx.x * blockDim.x + threadIdx.x;
    if (i >= Q) return;
    uint32_t key = key32(qh[i], qr[i], qt[i]);
    float v = -5.0f;
    if (key == EMPTY) {
        v = (*sent) ? 5.0f : -5.0f;
    } else {
        uint32_t slot = hash2(key) & tmask;
        while (true) {
            uint32_t kv = keys[slot];
            if (kv == key) { v = ((flagbits[slot >> 5] >> (slot & 31)) & 1u) ? 5.0f : -5.0f; break; }
            if (kv == EMPTY) break;   // shouldn't happen (key inserted in pass 1)
            slot = (slot + 1) & tmask;
        }
    }
    out[i] = v;
}

extern "C" void kernel_launch(void* const* d_in, const int* in_sizes, int n_in,
                              void* d_out, int out_size, void* d_ws, size_t ws_size,
                              hipStream_t stream) {
    const int* qh = (const int*)d_in[0];
    const int* qr = (const int*)d_in[1];
    const int* qt = (const int*)d_in[2];
    const int* data = (const int*)d_in[3];
    int Q = in_sizes[0];
    int N = in_sizes[3] / 3;
    const int* dh = data;
    const int* dr = data + (size_t)N;
    const int* dt = data + 2 * (size_t)N;
    float* out = (float*)d_out;

    // Size tiers: bloom 2^bb bits, table 2^tb u32 slots (tb >= 18: 100K keys, alpha <= 0.38).
    int bb = 22, tb = 19;
    size_t need = ((size_t)1 << (bb - 3)) + ((size_t)1 << (tb - 3)) + 256 + ((size_t)4 << tb);
    if (need > ws_size) { bb = 21; tb = 18;
        need = ((size_t)1 << (bb - 3)) + ((size_t)1 << (tb - 3)) + 256 + ((size_t)4 << tb); }
    if (need > ws_size) { bb = 20; tb = 18; }
    size_t bloomB = (size_t)1 << (bb - 3);
    size_t flagB  = (size_t)1 << (tb - 3);
    uint32_t bmask = ((uint32_t)1 << bb) - 1u;
    uint32_t tmask = ((uint32_t)1 << tb) - 1u;

    uint32_t* bloom    = (uint32_t*)d_ws;
    uint32_t* flagbits = (uint32_t*)((char*)d_ws + bloomB);
    uint32_t* sent     = (uint32_t*)((char*)d_ws + bloomB + flagB);
    uint32_t* keys     = (uint32_t*)((char*)d_ws + bloomB + flagB + 256);

    int zeroWords  = (int)((bloomB + flagB + 256) / 4);
    int totalWords = zeroWords + (1 << tb);
    k_zero<<<2048, 256, 0, stream>>>((uint32_t*)d_ws, zeroWords, totalWords);

    int qblocks = (Q + 255) / 256;
    k_insert<<<qblocks, 256, 0, stream>>>(qh, qr, qt, bloom, keys, sent, bmask, tmask, Q);

    int nquad = N / 4;
    k_scan<<<2048, 256, 0, stream>>>(dh, dr, dt, bloom, keys, flagbits, sent,
                                     bmask, tmask, nquad, N);

    k_out<<<qblocks, 256, 0, stream>>>(qh, qr, qt, keys, flagbits, sent, out, tmask, Q);
}

// Round 7
// 235.766 us; speedup vs baseline: 1.1983x; 1.0099x over previous
//
#include <hip/hip_runtime.h>
#include <stdint.h>

// PerfeCT membership: out[i] = +5.0 if (h,r,t) appears in data, else -5.0.
// Keys replicate the reference's int32 overflow: key32 = ((h*15000+r)*15000+t) mod 2^32.
// r6 diagnosis: replays run from L3 (FETCH~7KB) and k_scan is bound by 10M random
// per-lane global 4B bloom loads (transaction cost), not HBM. Fix: 128KB blocked-bloom
// bitmap REPLICATED INTO LDS per CU; one ds_read_b32 + 2-bit test per triple; exact
// u32 table (1MB, alpha=0.38) probed only on ~4% bloom hits, slot hash computed lazily.

typedef int iv4 __attribute__((ext_vector_type(4)));

#define EMPTY 0xFFFFFFFFu
#define BWORDS 32768   // 2^20-bit bloom = 128 KB (fits 160 KB LDS)

static __device__ __forceinline__ uint32_t mix32(uint32_t x) {
    x ^= x >> 16; x *= 0x85ebca6bu;
    x ^= x >> 13; x *= 0xc2b2ae35u;
    x ^= x >> 16;
    return x;
}
static __device__ __forceinline__ uint32_t hash2(uint32_t x) {  // table hash (lazy, cold path)
    return mix32(x ^ 0x9E3779B9u);
}
static __device__ __forceinline__ uint32_t key32(int h, int r, int t) {
    return ((uint32_t)h * 15000u + (uint32_t)r) * 15000u + (uint32_t)t;
}
// Blocked bloom: word index (bits 0..14) + 2 bit positions (15..19, 20..24) from one mix32.
static __device__ __forceinline__ void bloom_wm(uint32_t key, uint32_t* w, uint32_t* m) {
    uint32_t z = mix32(key);
    *w = z & (BWORDS - 1u);
    *m = (1u << ((z >> 15) & 31u)) | (1u << ((z >> 20) & 31u));
}

// ws layout: [bloom 128KB][flagbits (1<<tb)/8][sent 4B + pad 252][keys 4<<tb]
__global__ void k_zero(uint32_t* __restrict__ p, int zeroWords, int totalWords) {
    int stride = gridDim.x * blockDim.x;
    for (int i = blockIdx.x * blockDim.x + threadIdx.x; i < totalWords; i += stride)
        p[i] = (i < zeroWords) ? 0u : EMPTY;
}

__global__ void k_insert(const int* __restrict__ qh, const int* __restrict__ qr,
                         const int* __restrict__ qt,
                         uint32_t* __restrict__ bloom, uint32_t* __restrict__ keys,
                         uint32_t tmask, int Q) {
    int i = blockIdx.x * blockDim.x + threadIdx.x;
    if (i >= Q) return;
    uint32_t key = key32(qh[i], qr[i], qt[i]);
    if (key == EMPTY) return;      // sentinel-valued query: k_out consults `sent` directly
    uint32_t w, m; bloom_wm(key, &w, &m);
    atomicOr(&bloom[w], m);
    uint32_t slot = hash2(key) & tmask;
    while (true) {
        uint32_t prev = atomicCAS(&keys[slot], EMPTY, key);
        if (prev == EMPTY || prev == key) return;
        slot = (slot + 1) & tmask;
    }
}

static __device__ __forceinline__ void probe_mark(uint32_t key,
                                                  const uint32_t* __restrict__ keys,
                                                  uint32_t* __restrict__ flagbits,
                                                  uint32_t tmask) {
    uint32_t slot = hash2(key) & tmask;   // lazy: only computed on bloom hit
    while (true) {
        uint32_t v = keys[slot];
        if (v == key) { atomicOr(&flagbits[slot >> 5], 1u << (slot & 31)); return; }
        if (v == EMPTY) return;
        slot = (slot + 1) & tmask;
    }
}

// One block per CU (256 x 1024, 128KB LDS). Fill LDS bloom, then stream 4 triples/thread.
__global__ __launch_bounds__(1024) void k_scan(
        const int* __restrict__ dh, const int* __restrict__ dr,
        const int* __restrict__ dt,
        const uint32_t* __restrict__ bloom,
        const uint32_t* __restrict__ keys,
        uint32_t* __restrict__ flagbits, uint32_t* __restrict__ sent,
        uint32_t tmask, int nquad, int N) {
    __shared__ uint32_t lb[BWORDS];
    for (int i = threadIdx.x; i < BWORDS; i += 1024) lb[i] = bloom[i];
    __syncthreads();

    int stride = gridDim.x * blockDim.x;
    for (int j = blockIdx.x * blockDim.x + threadIdx.x; j < nquad; j += stride) {
        iv4 h4 = ((const iv4*)dh)[j];
        iv4 r4 = ((const iv4*)dr)[j];
        iv4 t4 = ((const iv4*)dt)[j];
        uint32_t k0 = key32(h4.x, r4.x, t4.x);
        uint32_t k1 = key32(h4.y, r4.y, t4.y);
        uint32_t k2 = key32(h4.z, r4.z, t4.z);
        uint32_t k3 = key32(h4.w, r4.w, t4.w);
        uint32_t w0, m0, w1, m1, w2, m2, w3, m3;
        bloom_wm(k0, &w0, &m0); bloom_wm(k1, &w1, &m1);
        bloom_wm(k2, &w2, &m2); bloom_wm(k3, &w3, &m3);
        uint32_t v0 = lb[w0], v1 = lb[w1], v2 = lb[w2], v3 = lb[w3];
        if (k0 == EMPTY) *sent = 1u; else if ((v0 & m0) == m0) probe_mark(k0, keys, flagbits, tmask);
        if (k1 == EMPTY) *sent = 1u; else if ((v1 & m1) == m1) probe_mark(k1, keys, flagbits, tmask);
        if (k2 == EMPTY) *sent = 1u; else if ((v2 & m2) == m2) probe_mark(k2, keys, flagbits, tmask);
        if (k3 == EMPTY) *sent = 1u; else if ((v3 & m3) == m3) probe_mark(k3, keys, flagbits, tmask);
    }
    int tail = N & 3;
    if (tail && blockIdx.x == 0 && threadIdx.x < (unsigned)tail) {
        int j = N - 1 - (int)threadIdx.x;
        uint32_t k = key32(dh[j], dr[j], dt[j]);
        if (k == EMPTY) *sent = 1u;
        else probe_mark(k, keys, flagbits, tmask);   // skip bloom on tail
    }
}

__global__ void k_out(const int* __restrict__ qh, const int* __restrict__ qr,
                      const int* __restrict__ qt,
                      const uint32_t* __restrict__ keys,
                      const uint32_t* __restrict__ flagbits,
                      const uint32_t* __restrict__ sent,
                      float* __restrict__ out, uint32_t tmask, int Q) {
    int i = blockIdx.x * blockDim.x + threadIdx.x;
    if (i >= Q) return;
    uint32_t key = key32(qh[i], qr[i], qt[i]);
    float v = -5.0f;
    if (key == EMPTY) {
        v = (*sent) ? 5.0f : -5.0f;
    } else {
        uint32_t slot = hash2(key) & tmask;
        while (true) {
            uint32_t kv = keys[slot];
            if (kv == key) { v = ((flagbits[slot >> 5] >> (slot & 31)) & 1u) ? 5.0f : -5.0f; break; }
            if (kv == EMPTY) break;   // shouldn't happen (inserted in pass 1)
            slot = (slot + 1) & tmask;
        }
    }
    out[i] = v;
}

extern "C" void kernel_launch(void* const* d_in, const int* in_sizes, int n_in,
                              void* d_out, int out_size, void* d_ws, size_t ws_size,
                              hipStream_t stream) {
    const int* qh = (const int*)d_in[0];
    const int* qr = (const int*)d_in[1];
    const int* qt = (const int*)d_in[2];
    const int* data = (const int*)d_in[3];
    int Q = in_sizes[0];
    int N = in_sizes[3] / 3;
    const int* dh = data;
    const int* dr = data + (size_t)N;
    const int* dt = data + 2 * (size_t)N;
    float* out = (float*)d_out;

    // Table 2^tb u32 slots; tb=18 -> alpha 0.38, 1MB. Floor tb=17 (livelock guard).
    int tb = 18;
    size_t bloomB = (size_t)BWORDS * 4;                       // 128 KB
    size_t need = bloomB + ((size_t)1 << (tb - 3)) + 256 + ((size_t)4 << tb);
    if (need > ws_size) tb = 17;
    size_t flagB = (size_t)1 << (tb - 3);
    uint32_t tmask = ((uint32_t)1 << tb) - 1u;

    uint32_t* bloom    = (uint32_t*)d_ws;
    uint32_t* flagbits = (uint32_t*)((char*)d_ws + bloomB);
    uint32_t* sent     = (uint32_t*)((char*)d_ws + bloomB + flagB);
    uint32_t* keys     = (uint32_t*)((char*)d_ws + bloomB + flagB + 256);

    int zeroWords  = (int)((bloomB + flagB + 256) / 4);
    int totalWords = zeroWords + (1 << tb);
    k_zero<<<1024, 256, 0, stream>>>((uint32_t*)d_ws, zeroWords, totalWords);

    int qblocks = (Q + 255) / 256;
    k_insert<<<qblocks, 256, 0, stream>>>(qh, qr, qt, bloom, keys, tmask, Q);

    int nquad = N / 4;
    k_scan<<<256, 1024, 0, stream>>>(dh, dr, dt, bloom, keys, flagbits, sent,
                                     tmask, nquad, N);

    k_out<<<qblocks, 256, 0, stream>>>(qh, qr, qt, keys, flagbits, sent, out, tmask, Q);
}

// Round 8
// 220.014 us; speedup vs baseline: 1.2841x; 1.0716x over previous
//
#include <hip/hip_runtime.h>
#include <stdint.h>

// PerfeCT membership: out[i] = +5.0 if (h,r,t) appears in data, else -5.0.
// key32 = ((h*15000+r)*15000+t) mod 2^32 (replicates reference's int32 overflow).
// r7 diagnosis: inline probe_mark stalls — P(any of 64 lanes probes) ~92% per site,
// so ~every wave-iteration ate ~600cyc of divergent random-load latency (1230 cyc/iter
// measured). Fix: DEFER probes — bloom hits go to a per-lane LDS queue (drained after
// the stream loop, latency hidden by TLP); overflow to a global list + k_probe kernel.
// Hot loop = coalesced loads + VALU + LDS bloom reads only.

typedef int iv4 __attribute__((ext_vector_type(4)));

#define EMPTY  0xFFFFFFFFu
#define BWORDS 32768     // 2^20-bit bloom = 128 KB LDS
#define QSLOTS 6
#define TPB    1024

static __device__ __forceinline__ uint32_t mix32(uint32_t x) {
    x ^= x >> 16; x *= 0x85ebca6bu;
    x ^= x >> 13; x *= 0xc2b2ae35u;
    x ^= x >> 16;
    return x;
}
static __device__ __forceinline__ uint32_t hash2(uint32_t x) {   // exact-table hash (cold path)
    return mix32(x ^ 0x9E3779B9u);
}
static __device__ __forceinline__ uint32_t key32(int h, int r, int t) {
    return ((uint32_t)h * 15000u + (uint32_t)r) * 15000u + (uint32_t)t;
}
static __device__ __forceinline__ void bloom_wm(uint32_t key, uint32_t* w, uint32_t* m) {
    uint32_t z = mix32(key);
    *w = z & (BWORDS - 1u);
    *m = (1u << ((z >> 15) & 31u)) | (1u << ((z >> 20) & 31u));
}

// ws: [bloom 128KB][flagbits (1<<tb)/8][hdr 256B: sent@0, ovf_cnt@4][keys 4<<tb][ovf 4*OVFCAP]
__global__ void k_zero(uint32_t* __restrict__ p, int zeroWords, int totalWords) {
    int stride = gridDim.x * blockDim.x;
    for (int i = blockIdx.x * blockDim.x + threadIdx.x; i < totalWords; i += stride)
        p[i] = (i < zeroWords) ? 0u : EMPTY;
}

__global__ void k_insert(const int* __restrict__ qh, const int* __restrict__ qr,
                         const int* __restrict__ qt,
                         uint32_t* __restrict__ bloom, uint32_t* __restrict__ keys,
                         uint32_t tmask, int Q) {
    int i = blockIdx.x * blockDim.x + threadIdx.x;
    if (i >= Q) return;
    uint32_t key = key32(qh[i], qr[i], qt[i]);
    if (key == EMPTY) return;       // sentinel-valued query: k_out consults `sent`
    uint32_t w, m; bloom_wm(key, &w, &m);
    atomicOr(&bloom[w], m);
    uint32_t slot = hash2(key) & tmask;
    while (true) {
        uint32_t prev = atomicCAS(&keys[slot], EMPTY, key);
        if (prev == EMPTY || prev == key) return;
        slot = (slot + 1) & tmask;
    }
}

static __device__ __forceinline__ void probe_mark(uint32_t key,
                                                  const uint32_t* __restrict__ keys,
                                                  uint32_t* __restrict__ flagbits,
                                                  uint32_t tmask) {
    uint32_t slot = hash2(key) & tmask;
    while (true) {
        uint32_t v = keys[slot];
        if (v == key) { atomicOr(&flagbits[slot >> 5], 1u << (slot & 31)); return; }
        if (v == EMPTY) return;
        slot = (slot + 1) & tmask;
    }
}

static __device__ __forceinline__ void ovf_push(uint32_t key,
                                                uint32_t* __restrict__ ovf_cnt,
                                                uint32_t* __restrict__ ovf, uint32_t ovfcap,
                                                const uint32_t* __restrict__ keys,
                                                uint32_t* __restrict__ flagbits, uint32_t tmask) {
    uint32_t idx = atomicAdd(ovf_cnt, 1u);
    if (idx < ovfcap) ovf[idx] = key;
    else probe_mark(key, keys, flagbits, tmask);   // cap exceeded: inline fallback
}

// One block/CU, 152 KB LDS. Stream 8 triples/thread (two int4 streams, MLP 6);
// bloom hits queued per-lane in LDS, drained after the loop.
__global__ __launch_bounds__(TPB) void k_scan(
        const int* __restrict__ dh, const int* __restrict__ dr,
        const int* __restrict__ dt,
        const uint32_t* __restrict__ bloom,
        const uint32_t* __restrict__ keys,
        uint32_t* __restrict__ flagbits, uint32_t* __restrict__ sent,
        uint32_t* __restrict__ ovf_cnt, uint32_t* __restrict__ ovf, uint32_t ovfcap,
        uint32_t tmask, int noct, int N) {
    __shared__ uint32_t lb[BWORDS];          // 128 KB
    __shared__ uint32_t qb[TPB * QSLOTS];    // 24 KB, slot-major (conflict-free)
    for (int i = threadIdx.x; i < BWORDS; i += TPB) lb[i] = bloom[i];
    __syncthreads();

    const iv4* H = (const iv4*)dh;
    const iv4* R = (const iv4*)dr;
    const iv4* T = (const iv4*)dt;
    int cnt = 0;
    int stride = gridDim.x * blockDim.x;

#define TESTQ(kk, vv, mm)                                                          \
    if ((kk) == EMPTY) *sent = 1u;                                                 \
    else if (((vv) & (mm)) == (mm)) {                                              \
        if (cnt < QSLOTS) qb[cnt * TPB + threadIdx.x] = (kk);                      \
        else ovf_push((kk), ovf_cnt, ovf, ovfcap, keys, flagbits, tmask);          \
        cnt++;                                                                     \
    }

    for (int j = blockIdx.x * blockDim.x + threadIdx.x; j < noct; j += stride) {
        iv4 hA = H[j], rA = R[j], tA = T[j];
        iv4 hB = H[j + noct], rB = R[j + noct], tB = T[j + noct];
        uint32_t k0 = key32(hA.x, rA.x, tA.x), k1 = key32(hA.y, rA.y, tA.y);
        uint32_t k2 = key32(hA.z, rA.z, tA.z), k3 = key32(hA.w, rA.w, tA.w);
        uint32_t k4 = key32(hB.x, rB.x, tB.x), k5 = key32(hB.y, rB.y, tB.y);
        uint32_t k6 = key32(hB.z, rB.z, tB.z), k7 = key32(hB.w, rB.w, tB.w);
        uint32_t w0,m0,w1,m1,w2,m2,w3,m3,w4,m4,w5,m5,w6,m6,w7,m7;
        bloom_wm(k0,&w0,&m0); bloom_wm(k1,&w1,&m1); bloom_wm(k2,&w2,&m2); bloom_wm(k3,&w3,&m3);
        bloom_wm(k4,&w4,&m4); bloom_wm(k5,&w5,&m5); bloom_wm(k6,&w6,&m6); bloom_wm(k7,&w7,&m7);
        uint32_t v0 = lb[w0], v1 = lb[w1], v2 = lb[w2], v3 = lb[w3];
        uint32_t v4 = lb[w4], v5 = lb[w5], v6 = lb[w6], v7 = lb[w7];
        TESTQ(k0, v0, m0) TESTQ(k1, v1, m1) TESTQ(k2, v2, m2) TESTQ(k3, v3, m3)
        TESTQ(k4, v4, m4) TESTQ(k5, v5, m5) TESTQ(k6, v6, m6) TESTQ(k7, v7, m7)
    }
#undef TESTQ

    // leftover elements [8*noct, N) — at most 11
    int rem = N - 8 * noct;
    if (blockIdx.x == 0 && (int)threadIdx.x < rem) {
        int j = 8 * noct + threadIdx.x;
        uint32_t k = key32(dh[j], dr[j], dt[j]);
        if (k == EMPTY) *sent = 1u;
        else probe_mark(k, keys, flagbits, tmask);
    }

    // drain per-lane queue (all waves concurrently -> latency hidden by TLP)
    int m = cnt < QSLOTS ? cnt : QSLOTS;
    for (int c = 0; c < m; ++c)
        probe_mark(qb[c * TPB + threadIdx.x], keys, flagbits, tmask);
}

__global__ void k_probe(const uint32_t* __restrict__ ovf,
                        const uint32_t* __restrict__ ovf_cnt, uint32_t ovfcap,
                        const uint32_t* __restrict__ keys,
                        uint32_t* __restrict__ flagbits, uint32_t tmask) {
    uint32_t n = *ovf_cnt; if (n > ovfcap) n = ovfcap;
    int stride = gridDim.x * blockDim.x;
    for (uint32_t i = blockIdx.x * blockDim.x + threadIdx.x; i < n; i += stride)
        probe_mark(ovf[i], keys, flagbits, tmask);
}

__global__ void k_out(const int* __restrict__ qh, const int* __restrict__ qr,
                      const int* __restrict__ qt,
                      const uint32_t* __restrict__ keys,
                      const uint32_t* __restrict__ flagbits,
                      const uint32_t* __restrict__ sent,
                      float* __restrict__ out, uint32_t tmask, int Q) {
    int i = blockIdx.x * blockDim.x + threadIdx.x;
    if (i >= Q) return;
    uint32_t key = key32(qh[i], qr[i], qt[i]);
    float v = -5.0f;
    if (key == EMPTY) {
        v = (*sent) ? 5.0f : -5.0f;
    } else {
        uint32_t slot = hash2(key) & tmask;
        while (true) {
            uint32_t kv = keys[slot];
            if (kv == key) { v = ((flagbits[slot >> 5] >> (slot & 31)) & 1u) ? 5.0f : -5.0f; break; }
            if (kv == EMPTY) break;
            slot = (slot + 1) & tmask;
        }
    }
    out[i] = v;
}

extern "C" void kernel_launch(void* const* d_in, const int* in_sizes, int n_in,
                              void* d_out, int out_size, void* d_ws, size_t ws_size,
                              hipStream_t stream) {
    const int* qh = (const int*)d_in[0];
    const int* qr = (const int*)d_in[1];
    const int* qt = (const int*)d_in[2];
    const int* data = (const int*)d_in[3];
    int Q = in_sizes[0];
    int N = in_sizes[3] / 3;
    const int* dh = data;
    const int* dr = data + (size_t)N;
    const int* dt = data + 2 * (size_t)N;
    float* out = (float*)d_out;

    int tb = 18;                               // 100K keys, alpha 0.38; floor 17 (livelock guard)
    uint32_t ovfcap = 65536;
    size_t bloomB = (size_t)BWORDS * 4;        // 128 KB
    size_t need = bloomB + ((size_t)1 << (tb - 3)) + 256 + ((size_t)4 << tb) + 4ull * ovfcap;
    if (need > ws_size) { ovfcap = 8192;
        need = bloomB + ((size_t)1 << (tb - 3)) + 256 + ((size_t)4 << tb) + 4ull * ovfcap; }
    if (need > ws_size) { tb = 17; }
    size_t flagB = (size_t)1 << (tb - 3);
    uint32_t tmask = ((uint32_t)1 << tb) - 1u;

    uint32_t* bloom    = (uint32_t*)d_ws;
    uint32_t* flagbits = (uint32_t*)((char*)d_ws + bloomB);
    uint32_t* hdr      = (uint32_t*)((char*)d_ws + bloomB + flagB);     // sent@0, ovf_cnt@1
    uint32_t* keys     = (uint32_t*)((char*)d_ws + bloomB + flagB + 256);
    uint32_t* ovf      = (uint32_t*)((char*)d_ws + bloomB + flagB + 256 + ((size_t)4 << tb));

    int zeroWords  = (int)((bloomB + flagB + 256) / 4);
    int totalWords = zeroWords + (1 << tb);    // ovf needs no init (counter zeroed)
    k_zero<<<1024, 256, 0, stream>>>((uint32_t*)d_ws, zeroWords, totalWords);

    int qblocks = (Q + 255) / 256;
    k_insert<<<qblocks, 256, 0, stream>>>(qh, qr, qt, bloom, keys, tmask, Q);

    int noct = N / 8;
    k_scan<<<256, TPB, 0, stream>>>(dh, dr, dt, bloom, keys, flagbits,
                                    hdr, hdr + 1, ovf, ovfcap, tmask, noct, N);

    k_probe<<<64, 256, 0, stream>>>(ovf, hdr + 1, ovfcap, keys, flagbits, tmask);

    k_out<<<qblocks, 256, 0, stream>>>(qh, qr, qt, keys, flagbits, hdr, out, tmask, Q);
}